// Round 5
// baseline (2550.510 us; speedup 1.0000x reference)
//
#include <hip/hip_runtime.h>
#include <math.h>

#define NN 128
#define VV (NN*NN*NN)            // 2,097,152 voxels per volume

#define K_GAMMA 1e-3f
#define K_ALPHA 1e-2f
#define K_DTN3  5.9604644775390625e-08f   // (1/8) / 128^3  == 2^-24
#define K_W0    0.04908738521234052f      // 2*pi/128

// ---------------- FFT helpers (radix-2, N=128, 64 lanes per line) -----------
// Forward: DIF, natural input -> bit-reversed output, twiddle exp(-i theta).
// Inverse: DIT, bit-reversed input -> natural output, twiddle exp(+i theta),
// unnormalized (1/N^3 folded into the spectral scale).
__device__ __forceinline__ void fft128_fwd(float* re, float* im, const int stride,
                                           const int lane,
                                           const float* __restrict__ twr,
                                           const float* __restrict__ twi) {
#pragma unroll
  for (int lh = 6; lh >= 0; --lh) {
    __syncthreads();
    const int h  = 1 << lh;
    const int j  = lane & (h - 1);
    const int i0 = ((lane - j) << 1) + j;
    const int i1 = i0 + h;
    const int tw = j << (6 - lh);
    const float wr = twr[tw], ws = twi[tw];
    const int a = i0 * stride, b = i1 * stride;
    const float ar = re[a], ai = im[a];
    const float br = re[b], bi = im[b];
    re[a] = ar + br;
    im[a] = ai + bi;
    const float dr = ar - br, di = ai - bi;
    re[b] = dr * wr + di * ws;   // (dr + i di) * (wr - i ws)
    im[b] = di * wr - dr * ws;
  }
  __syncthreads();
}

__device__ __forceinline__ void fft128_inv(float* re, float* im, const int stride,
                                           const int lane,
                                           const float* __restrict__ twr,
                                           const float* __restrict__ twi) {
#pragma unroll
  for (int lh = 0; lh <= 6; ++lh) {
    __syncthreads();
    const int h  = 1 << lh;
    const int j  = lane & (h - 1);
    const int i0 = ((lane - j) << 1) + j;
    const int i1 = i0 + h;
    const int tw = j << (6 - lh);
    const float wr = twr[tw], ws = twi[tw];
    const int a = i0 * stride, b = i1 * stride;
    const float ar = re[a], ai = im[a];
    const float br = re[b], bi = im[b];
    const float cr = br * wr - bi * ws;  // (br + i bi) * (wr + i ws)
    const float ci = br * ws + bi * wr;
    re[a] = ar + cr;
    im[a] = ai + ci;
    re[b] = ar - cr;
    im[b] = ai - ci;
  }
  __syncthreads();
}

__device__ __forceinline__ void make_twiddles(int tid, float* twr, float* twi) {
  if (tid < 64) {
    float s, c;
    sincosf((float)tid * K_W0, &s, &c);
    twr[tid] = c;
    twi[tid] = s;
  }
}

// ---------------- K1: m = L v = gamma*v + alpha*(6v - sum of 6 nbrs) --------
__global__ __launch_bounds__(256) void k_stencil_L(const float* __restrict__ v,
                                                   float* __restrict__ m) {
  const int idx = blockIdx.x * 256 + threadIdx.x;   // over 6*VV
  const int vox = idx & (VV - 1);
  const int r   = idx >> 21;
  const int z = vox & 127, y = (vox >> 7) & 127, x = vox >> 14;
  const float* base = v + (size_t)r * VV;
  const float c = base[vox];
  const int xm = (x - 1) & 127, xp = (x + 1) & 127;
  const int ym = (y - 1) & 127, yp = (y + 1) & 127;
  const int zm = (z - 1) & 127, zp = (z + 1) & 127;
  const float nsum = base[(xm << 14) | (y << 7) | z] + base[(xp << 14) | (y << 7) | z]
                   + base[(x << 14) | (ym << 7) | z] + base[(x << 14) | (yp << 7) | z]
                   + base[(x << 14) | (y << 7) | zm] + base[(x << 14) | (y << 7) | zp];
  m[idx] = K_GAMMA * c + K_ALPHA * (6.0f * c - nsum);
}

// ---------------- K2: pack 2 real vols -> complex, forward FFT along z ------
__global__ __launch_bounds__(256) void k_fft_z_fwd(const float* __restrict__ m,
                                                   float2* __restrict__ cbuf) {
  __shared__ float twr[64], twi[64];
  __shared__ float re[4][128], im[4][128];
  const int tid = threadIdx.x, lane = tid & 63, w = tid >> 6;
  make_twiddles(tid, twr, twi);
  const int line = blockIdx.x * 4 + w;        // ((p*128 + x)*128 + y)
  const int p = line >> 14;
  const float* r0 = m + (size_t)(2 * p) * VV + (size_t)(line & 16383) * 128;
  const float* r1 = r0 + VV;
  re[w][lane] = r0[lane];  re[w][lane + 64] = r0[lane + 64];
  im[w][lane] = r1[lane];  im[w][lane + 64] = r1[lane + 64];
  fft128_fwd(re[w], im[w], 1, lane, twr, twi);
  float2* dst = cbuf + (size_t)line * 128;
  dst[lane]      = make_float2(re[w][lane],      im[w][lane]);
  dst[lane + 64] = make_float2(re[w][lane + 64], im[w][lane + 64]);
}

// ---------------- K3/K5: FFT along y (tiled, in-place) ----------------------
template <bool INV>
__global__ __launch_bounds__(512) void k_fft_y(float2* __restrict__ cbuf) {
  __shared__ float twr[64], twi[64];
  __shared__ float re[128 * 9], im[128 * 9];
  const int tid = threadIdx.x, lane = tid & 63, wv = tid >> 6;
  make_twiddles(tid, twr, twi);
  const int bid = blockIdx.x;                 // 3 * 128 * 16
  const int p = bid >> 11, rem = bid & 2047;
  const int x = rem >> 4, z0 = (rem & 15) << 3;
  float2* base = cbuf + (size_t)p * VV + (size_t)x * 16384 + z0;
  {
    int e = tid;       int y = e >> 3, zz = e & 7;
    float2 val = base[y * 128 + zz];
    re[y * 9 + zz] = val.x;  im[y * 9 + zz] = val.y;
    e = tid + 512;     y = e >> 3; zz = e & 7;
    val = base[y * 128 + zz];
    re[y * 9 + zz] = val.x;  im[y * 9 + zz] = val.y;
  }
  if (INV) fft128_inv(re + wv, im + wv, 9, lane, twr, twi);
  else     fft128_fwd(re + wv, im + wv, 9, lane, twr, twi);
  {
    int e = tid;       int y = e >> 3, zz = e & 7;
    base[y * 128 + zz] = make_float2(re[y * 9 + zz], im[y * 9 + zz]);
    e = tid + 512;     y = e >> 3; zz = e & 7;
    base[y * 128 + zz] = make_float2(re[y * 9 + zz], im[y * 9 + zz]);
  }
}

// ---------------- K4: fused fwd-x FFT, spectral scale, inv-x FFT ------------
// Scale is evaluated at bit-reversed storage positions for all 3 axes:
// tt[p] = 2-2cos(2*pi*bitrev7(p)/128), so tt[storage_pos] == t(true freq).
__global__ __launch_bounds__(512) void k_fft_x_fused(float2* __restrict__ cbuf) {
  __shared__ float twr[64], twi[64], tt[128];
  __shared__ float re[128 * 9], im[128 * 9];
  const int tid = threadIdx.x, lane = tid & 63, wv = tid >> 6;
  make_twiddles(tid, twr, twi);
  if (tid < 128) {
    const int br = (int)(__brev((unsigned)tid) >> 25);   // 7-bit bit-reverse
    tt[tid] = 2.0f - 2.0f * cosf((float)br * K_W0);
  }
  const int bid = blockIdx.x;
  const int p = bid >> 11, rem = bid & 2047;
  const int y = rem >> 4, z0 = (rem & 15) << 3;
  float2* base = cbuf + (size_t)p * VV + (size_t)y * 128 + z0;
  {
    int e = tid;       int xx = e >> 3, zz = e & 7;
    float2 val = base[(size_t)xx * 16384 + zz];
    re[xx * 9 + zz] = val.x;  im[xx * 9 + zz] = val.y;
    e = tid + 512;     xx = e >> 3; zz = e & 7;
    val = base[(size_t)xx * 16384 + zz];
    re[xx * 9 + zz] = val.x;  im[xx * 9 + zz] = val.y;
  }
  fft128_fwd(re + wv, im + wv, 9, lane, twr, twi);
  // spectral scale: dt / (N^3 * (gamma + alpha*(tx+ty+tz)))
  {
    const float tyv = tt[y];
    const float tzv = tt[z0 + wv];
#pragma unroll
    for (int i = lane; i < 128; i += 64) {
      const float sc = K_DTN3 / (K_GAMMA + K_ALPHA * (tt[i] + tyv + tzv));
      re[i * 9 + wv] *= sc;
      im[i * 9 + wv] *= sc;
    }
  }
  fft128_inv(re + wv, im + wv, 9, lane, twr, twi);
  {
    int e = tid;       int xx = e >> 3, zz = e & 7;
    base[(size_t)xx * 16384 + zz] = make_float2(re[xx * 9 + zz], im[xx * 9 + zz]);
    e = tid + 512;     xx = e >> 3; zz = e & 7;
    base[(size_t)xx * 16384 + zz] = make_float2(re[xx * 9 + zz], im[xx * 9 + zz]);
  }
}

// ---------------- K6: inverse FFT along z, in place (sv stays packed) -------
__global__ __launch_bounds__(256) void k_fft_z_inv(float2* __restrict__ cbuf) {
  __shared__ float twr[64], twi[64];
  __shared__ float re[4][128], im[4][128];
  const int tid = threadIdx.x, lane = tid & 63, w = tid >> 6;
  make_twiddles(tid, twr, twi);
  const int line = blockIdx.x * 4 + w;
  float2* src = cbuf + (size_t)line * 128;
  float2 v0 = src[lane], v1 = src[lane + 64];
  re[w][lane] = v0.x;  im[w][lane] = v0.y;
  re[w][lane + 64] = v1.x;  im[w][lane + 64] = v1.y;
  fft128_inv(re[w], im[w], 1, lane, twr, twi);
  src[lane]      = make_float2(re[w][lane],      im[w][lane]);
  src[lane + 64] = make_float2(re[w][lane + 64], im[w][lane + 64]);
}

// ---------------- K7: pullback of phi and m by sv (packed in cbuf) ----------
// JAX map_coordinates(order=1, mode='wrap'): index % size on floor/floor+1,
// weights from the unwrapped coordinate -> (&127) with lerp.
__global__ __launch_bounds__(256) void k_pullback(const float* __restrict__ svc,
                                                  const float* __restrict__ phiA,
                                                  const float* __restrict__ mA,
                                                  float* __restrict__ phiB,
                                                  float* __restrict__ mB) {
  const int idx = blockIdx.x * 256 + threadIdx.x;   // over 2*VV
  const int b   = idx >> 21;
  const int vox = idx & (VV - 1);
  const int z = vox & 127, y = (vox >> 7) & 127, x = vox >> 14;
  // sv channel r=b*3+c lives at complex vol r>>1, component r&1
  const int r0 = b * 3;
  const float d0 = svc[(size_t)((r0)     >> 1) * 2 * VV + ((size_t)vox << 1) + ((r0)     & 1)];
  const float d1 = svc[(size_t)((r0 + 1) >> 1) * 2 * VV + ((size_t)vox << 1) + ((r0 + 1) & 1)];
  const float d2 = svc[(size_t)((r0 + 2) >> 1) * 2 * VV + ((size_t)vox << 1) + ((r0 + 2) & 1)];
  const float cx = (float)x + d0, cy = (float)y + d1, cz = (float)z + d2;
  const float flx = floorf(cx), fly = floorf(cy), flz = floorf(cz);
  const float wx = cx - flx, wy = cy - fly, wz = cz - flz;
  const int x0 = ((int)flx) & 127, y0 = ((int)fly) & 127, z0 = ((int)flz) & 127;
  const int x1 = (x0 + 1) & 127,  y1 = (y0 + 1) & 127,  z1 = (z0 + 1) & 127;
  const int o000 = (x0 * 128 + y0) * 128 + z0;
  const int o001 = (x0 * 128 + y0) * 128 + z1;
  const int o010 = (x0 * 128 + y1) * 128 + z0;
  const int o011 = (x0 * 128 + y1) * 128 + z1;
  const int o100 = (x1 * 128 + y0) * 128 + z0;
  const int o101 = (x1 * 128 + y0) * 128 + z1;
  const int o110 = (x1 * 128 + y1) * 128 + z0;
  const int o111 = (x1 * 128 + y1) * 128 + z1;
  const float w000 = (1.f - wx) * (1.f - wy) * (1.f - wz);
  const float w001 = (1.f - wx) * (1.f - wy) * wz;
  const float w010 = (1.f - wx) * wy * (1.f - wz);
  const float w011 = (1.f - wx) * wy * wz;
  const float w100 = wx * (1.f - wy) * (1.f - wz);
  const float w101 = wx * (1.f - wy) * wz;
  const float w110 = wx * wy * (1.f - wz);
  const float w111 = wx * wy * wz;
  const size_t sb = (size_t)b * 3 * VV;
  const float dd[3] = {d0, d1, d2};
#pragma unroll
  for (int c = 0; c < 3; ++c) {
    const size_t vb = sb + (size_t)c * VV;
    const float* P = phiA + vb;
    const float gp = w000 * P[o000] + w001 * P[o001] + w010 * P[o010] + w011 * P[o011]
                   + w100 * P[o100] + w101 * P[o101] + w110 * P[o110] + w111 * P[o111];
    phiB[vb + vox] = gp + dd[c];
    const float* M = mA + vb;
    const float gm = w000 * M[o000] + w001 * M[o001] + w010 * M[o010] + w011 * M[o011]
                   + w100 * M[o100] + w101 * M[o101] + w110 * M[o110] + w111 * M[o111];
    mB[vb + vox] = gm;
  }
}

// ---------------- host ------------------------------------------------------
// ws layout (floats): [phi1: 6*VV][mA: 6*VV][mB: 6*VV][cbuf: 3*VV complex]
// total 4 * 6*VV * 4B = 201,326,592 bytes (192 MiB).
extern "C" void kernel_launch(void* const* d_in, const int* in_sizes, int n_in,
                              void* d_out, int out_size, void* d_ws, size_t ws_size,
                              hipStream_t stream) {
  (void)in_sizes; (void)n_in; (void)out_size; (void)ws_size;
  const float* v = (const float*)d_in[0];
  float* phi0 = (float*)d_out;                       // phi buffer A (result here)
  float* ws   = (float*)d_ws;
  const size_t FV = (size_t)6 * VV;                  // floats per full field
  float* phi1 = ws;                                  // phi buffer B
  float* mA   = ws + FV;
  float* mB   = ws + 2 * FV;
  float2* cbuf = (float2*)(ws + 3 * FV);             // 3 complex vols (= sv packed)

  hipMemsetAsync(phi0, 0, FV * sizeof(float), stream);
  k_stencil_L<<<dim3((unsigned)(FV / 256)), dim3(256), 0, stream>>>(v, mA);

  float* phiA = phi0; float* phiB = phi1;
  float* ma = mA;     float* mb = mB;
  for (int s = 0; s < 8; ++s) {
    k_fft_z_fwd<<<dim3(12288), dim3(256), 0, stream>>>(ma, cbuf);
    k_fft_y<false><<<dim3(6144), dim3(512), 0, stream>>>(cbuf);
    k_fft_x_fused<<<dim3(6144), dim3(512), 0, stream>>>(cbuf);
    k_fft_y<true><<<dim3(6144), dim3(512), 0, stream>>>(cbuf);
    k_fft_z_inv<<<dim3(12288), dim3(256), 0, stream>>>(cbuf);
    k_pullback<<<dim3(16384), dim3(256), 0, stream>>>((const float*)cbuf, phiA, ma, phiB, mb);
    float* t = phiA; phiA = phiB; phiB = t;
    t = ma; ma = mb; mb = t;
  }
  // 8 swaps (even): final phi ends in d_out
}